// Round 5
// baseline (469.081 us; speedup 1.0000x reference)
//
#include <hip/hip_runtime.h>

// AUGRU fused scan, MI355X/gfx950.  R9 (= R8 resubmit + LDS 16B-align hardening).
//
// R5/R6/R7 invariant: ~2900 cy/step regardless of tile size, barrier flavor,
// or blocks/CU -> the cost is the block-wide sync structure itself (2x
// s_barrier + LDS round-trips with 1 wave/SIMD, nothing absorbs skew/latency).
//
// R8/R9 structure: each wave owns 4 whole sequences (all 64 h-cols). Sequences
// sit at A-rows {0,4,8,12}; C-layout reg0 then gives every lane one
// (seq=lg, col=16nt+lr) slot per n-tile -> scalar phases fully dense (12
// transcendentals/lane/step, same as R7). h and r*h exchanges are wave-
// private LDS round-trips (same-wave DS ordering + compiler lgkmcnt) ->
// ZERO s_barrier / __syncthreads in the kernel. Each wave carries the full
// weight set as B-frags (192 VGPR; AGPR demotion harmless - MFMA reads
// AGPRs). 48 MFMA/wave/step (pipe was 7% busy - free). 1 wave/SIMD.
//
// R9 hardening: explicit __align__(16) on all LDS arrays (ds_read_b128 on
// _Float16 arrays otherwise only has 2B guaranteed alignment - fault risk).
//
// Layouts (verified R5-R7, absmax 0.0039): A/B frag k=(lane>>4)*8+j
// contiguous; C/D col=lane&15, row=(lane>>4)*4+reg. LDS tiles [5][64] f16
// (rows 0..3 = seqs, row 4 = zeros, feeds A-rows lr%4!=0), XOR swizzle
// byte ^= (row&7)<<4 (frag reads conflict-free: same-address broadcast on
// row 4 + distinct banks on rows 0..3).

typedef _Float16 half4_t __attribute__((ext_vector_type(4)));
typedef _Float16 half8_t __attribute__((ext_vector_type(8)));
typedef float    f32x4  __attribute__((ext_vector_type(4)));

#define T_MAX 200
#define H_DIM 64

__device__ __forceinline__ f32x4 mfma16(half8_t a, half8_t b, f32x4 c) {
    return __builtin_amdgcn_mfma_f32_16x16x32_f16(a, b, c, 0, 0, 0);
}
__device__ __forceinline__ float sigm(float x) {
    return __fdividef(1.f, 1.f + __expf(-x));
}

__global__ __launch_bounds__(256, 1) void augru_wave(
    const float* __restrict__ X,    // (B,200,64) fp32
    const int*   __restrict__ SL,   // (B,1) int32
    const float* __restrict__ ATT,  // (B,200,1) fp32
    const float* __restrict__ WG,   // (128,128) fp32
    const float* __restrict__ BG,   // (128,) fp32
    const float* __restrict__ WC,   // (128,64) fp32
    const float* __restrict__ BC,   // (64,) fp32
    float*       __restrict__ OUT)  // (B,200,64) fp32
{
    const int tid = threadIdx.x;
    const int w   = tid >> 6;      // wave 0..3 (fully independent)
    const int l   = tid & 63;
    const int lr  = l & 15;        // A-frag row / C col
    const int lg  = l >> 4;        // frag k-group; also THIS LANE'S SEQ index
    const int sb  = blockIdx.x * 16 + 4 * w;   // wave's first sequence

    // per-wave private LDS (no cross-wave traffic, no barriers)
    __shared__ __align__(16) _Float16 xb[4][2][5 * 64];  // x(t) dbuf; row4=0
    __shared__ __align__(16) _Float16 hb[4][5 * 64];     // h(t)
    __shared__ __align__(16) _Float16 rhb[4][5 * 64];    // r*h
    __shared__ __align__(16) float    att_s[4][4][T_MAX];

    // ---- zero tiles (row 4 stays 0 forever; h rows = h(0) = 0) ----
    for (int i = l; i < 5 * 64; i += 64) {
        xb[w][0][i] = (_Float16)0.f; xb[w][1][i] = (_Float16)0.f;
        hb[w][i]    = (_Float16)0.f; rhb[w][i]   = (_Float16)0.f;
    }
#pragma unroll
    for (int s = 0; s < 4; ++s) {
        const float* ap = ATT + (size_t)(sb + s) * T_MAX;
        for (int c = l; c < T_MAX; c += 64) att_s[w][s][c] = ap[c];
    }
    int Ls[4]; int Lw = 0;
#pragma unroll
    for (int s = 0; s < 4; ++s) {
        int v = SL[sb + s];
        v = v < 0 ? 0 : (v > T_MAX ? T_MAX : v);
        Ls[s] = v; Lw = max(Lw, v);
    }

    // ---- full weight set as B-frags (per wave): wg[nt 0..7][kt 0..3] ----
    // gate col = 16*nt + lr  (nt 0..3 = r, 4..7 = u); cand col = 16*nt + lr
    half8_t wg[8][4], wc[4][4];
    float   bgv[8], bcv[4];
#pragma unroll
    for (int nt = 0; nt < 8; ++nt) {
        const int col = 16 * nt + lr;
#pragma unroll
        for (int kt = 0; kt < 4; ++kt) {
            const int kb = 32 * kt + 8 * lg;
            half8_t f;
#pragma unroll
            for (int j = 0; j < 8; ++j) f[j] = (_Float16)WG[(size_t)(kb + j) * 128 + col];
            wg[nt][kt] = f;
        }
        bgv[nt] = BG[col];
    }
#pragma unroll
    for (int nt = 0; nt < 4; ++nt) {
        const int col = 16 * nt + lr;
#pragma unroll
        for (int kt = 0; kt < 4; ++kt) {
            const int kb = 32 * kt + 8 * lg;
            half8_t f;
#pragma unroll
            for (int j = 0; j < 8; ++j) f[j] = (_Float16)WC[(size_t)(kb + j) * 64 + col];
            wc[nt][kt] = f;
        }
        bcv[nt] = BC[col];
    }

    // ---- hoisted LDS byte addresses ----
    // A-frag read: row' = lr/4 if lr%4==0 else 4 (zero row)
    const int rowp = ((lr & 3) == 0) ? (lr >> 2) : 4;
    const int off0 = rowp * 128 + ((16 * lg) ^ (rowp << 4));        // k-tile 0
    const int off1 = rowp * 128 + ((64 + 16 * lg) ^ (rowp << 4));   // k-tile 1
    // scalar writes: this lane's seq = lg -> tile row lg, col 16*nt+lr
    int a_wr[4];
#pragma unroll
    for (int nt = 0; nt < 4; ++nt)
        a_wr[nt] = lg * 128 + ((32 * nt + 2 * lr) ^ (lg << 4));
    // x staging: lane (lg,lr) carries x[seq=lg][4lr..4lr+3]
    const int a_xs = lg * 128 + ((8 * lr) ^ (lg << 4));
    const float* xsrc = X + (size_t)(sb + lg) * (T_MAX * H_DIM) + 4 * lr;

    // ---- stage x(0), prefetch x(1) ----
    {
        float4 v0 = *(const float4*)xsrc;
        half4_t h4 = { (_Float16)v0.x, (_Float16)v0.y, (_Float16)v0.z, (_Float16)v0.w };
        *(half4_t*)((char*)xb[w][0] + a_xs) = h4;
    }
    float4 xv1 = *(const float4*)(xsrc + H_DIM);

    float  hown[4] = {0.f, 0.f, 0.f, 0.f};   // h[seq=lg][16nt+lr]
    const int   Lme   = Ls[lg];
    const size_t obase = (size_t)(sb + lg) * (T_MAX * H_DIM) + lr;

    for (int t = 0; t < Lw; ++t) {
        const int cur = t & 1;
        int tn2 = t + 2; if (tn2 > T_MAX - 1) tn2 = T_MAX - 1;
        float4 xv2 = *(const float4*)(xsrc + (size_t)tn2 * H_DIM);   // in flight

        // ---- frags ----
        char* xB = (char*)xb[w][cur];
        half8_t ax0 = *(half8_t*)(xB + off0);
        half8_t ax1 = *(half8_t*)(xB + off1);
        half8_t ah0 = *(half8_t*)((char*)hb[w] + off0);
        half8_t ah1 = *(half8_t*)((char*)hb[w] + off1);

        // ---- gate MFMAs (8 n-tiles x K=128) + cand x-part ----
        f32x4 g[8];
#pragma unroll
        for (int nt = 0; nt < 8; ++nt) {
            f32x4 a = { bgv[nt], bgv[nt], bgv[nt], bgv[nt] };
            a = mfma16(ax0, wg[nt][0], a);
            a = mfma16(ax1, wg[nt][1], a);
            a = mfma16(ah0, wg[nt][2], a);
            a = mfma16(ah1, wg[nt][3], a);
            g[nt] = a;
        }
        f32x4 cc[4];
#pragma unroll
        for (int nt = 0; nt < 4; ++nt) {
            f32x4 a = { bcv[nt], bcv[nt], bcv[nt], bcv[nt] };
            a = mfma16(ax0, wc[nt][0], a);
            a = mfma16(ax1, wc[nt][1], a);
            cc[nt] = a;
        }

        // ---- pointwise (dense: every lane = one (seq,col) per n-tile) ----
        const float at = att_s[w][lg][t];
        float uu[4];
#pragma unroll
        for (int nt = 0; nt < 4; ++nt) {
            float rv = sigm(g[nt][0]);
            *(_Float16*)((char*)rhb[w] + a_wr[nt]) = (_Float16)(rv * hown[nt]);
            uu[nt] = (1.f - at) * sigm(g[4 + nt][0]);
        }

        // ---- cand r*h-part (same-wave LDS round-trip, no barrier) ----
        half8_t ar0 = *(half8_t*)((char*)rhb[w] + off0);
        half8_t ar1 = *(half8_t*)((char*)rhb[w] + off1);
#pragma unroll
        for (int nt = 0; nt < 4; ++nt) {
            cc[nt] = mfma16(ar0, wc[nt][2], cc[nt]);
            cc[nt] = mfma16(ar1, wc[nt][3], cc[nt]);
        }

        // ---- tanh, h update, store, republish h ----
#pragma unroll
        for (int nt = 0; nt < 4; ++nt) {
            float z  = cc[nt][0];
            float az = fabsf(z);
            float e2 = __expf(2.f * az);
            float c  = copysignf(1.f - __fdividef(2.f, e2 + 1.f), z);
            float hn = uu[nt] * hown[nt] + (1.f - uu[nt]) * c;
            bool  m  = (t < Lme);
            OUT[obase + (size_t)t * H_DIM + 16 * nt] = m ? hn : 0.f;
            if (m) hown[nt] = hn;
            *(_Float16*)((char*)hb[w] + a_wr[nt]) = (_Float16)hown[nt];
        }

        // ---- stage x(t+1) into the other buffer ----
        {
            half4_t h4 = { (_Float16)xv1.x, (_Float16)xv1.y, (_Float16)xv1.z, (_Float16)xv1.w };
            *(half4_t*)((char*)xb[w][cur ^ 1] + a_xs) = h4;
        }
        xv1 = xv2;
    }

    // ---- zero-fill t in [Lw, 200) for this wave's 4 sequences ----
    {
        uint4 zz = make_uint4(0u, 0u, 0u, 0u);
        const int n4 = (T_MAX - Lw) * (H_DIM / 4);
#pragma unroll
        for (int s = 0; s < 4; ++s) {
            uint4* zp = (uint4*)(OUT + ((size_t)(sb + s) * T_MAX + Lw) * H_DIM);
            for (int i = l; i < n4; i += 64) zp[i] = zz;
        }
    }
}

extern "C" void kernel_launch(void* const* d_in, const int* in_sizes, int n_in,
                              void* d_out, int out_size, void* d_ws, size_t ws_size,
                              hipStream_t stream) {
    const float* X   = (const float*)d_in[0];
    const int*   SL  = (const int*)d_in[1];
    const float* ATT = (const float*)d_in[2];
    const float* WG  = (const float*)d_in[3];
    const float* BG  = (const float*)d_in[4];
    const float* WC  = (const float*)d_in[5];
    const float* BC  = (const float*)d_in[6];
    float*       OUT = (float*)d_out;

    const int B = in_sizes[1];   // sequence_length has B*1 elements
    dim3 grid(B / 16), block(256);
    augru_wave<<<grid, block, 0, stream>>>(X, SL, ATT, WG, BG, WC, BC, OUT);
}